// Round 8
// baseline (471.494 us; speedup 1.0000x reference)
//
#include <hip/hip_runtime.h>
#include <math.h>

namespace {

constexpr int Na = 50000, Np = 100000, L = 2, E = 150000;
constexpr int SCAN_TILE = 2048;

typedef __attribute__((ext_vector_type(8))) short short8v;
typedef __attribute__((ext_vector_type(4))) float f32x4;

__device__ inline float geluf(float x){ return 0.5f*x*(1.0f + erff(x*0.7071067811865476f)); }

__device__ inline float bf2f(unsigned short u){ return __uint_as_float(((unsigned)u) << 16); }
__device__ inline unsigned short f2bf(float f){
  unsigned u = __float_as_uint(f);
  u += 0x7FFFu + ((u >> 16) & 1u);   // round-to-nearest-even
  return (unsigned short)(u >> 16);
}

struct StF32 {
  using T = float;
  static __device__ float ld(const T* p){ return *p; }
  static __device__ void st(T* p, float v){ *p = v; }
  static __device__ short8v ld8(const T* __restrict__ p){
    float4 lo = *reinterpret_cast<const float4*>(p);
    float4 hi = *reinterpret_cast<const float4*>(p+4);
    short8v v;
    v[0]=(short)f2bf(lo.x); v[1]=(short)f2bf(lo.y); v[2]=(short)f2bf(lo.z); v[3]=(short)f2bf(lo.w);
    v[4]=(short)f2bf(hi.x); v[5]=(short)f2bf(hi.y); v[6]=(short)f2bf(hi.z); v[7]=(short)f2bf(hi.w);
    return v;
  }
  static __device__ void ld16(const T* __restrict__ p, float* o){
    const float4* q = reinterpret_cast<const float4*>(p);
    #pragma unroll
    for (int i = 0; i < 4; ++i){
      float4 v = q[i];
      o[4*i] = v.x; o[4*i+1] = v.y; o[4*i+2] = v.z; o[4*i+3] = v.w;
    }
  }
};
struct StBF16 {
  using T = unsigned short;
  static __device__ float ld(const T* p){ return bf2f(*p); }
  static __device__ void st(T* p, float v){ *p = f2bf(v); }
  static __device__ short8v ld8(const T* __restrict__ p){
    return *reinterpret_cast<const short8v*>(p);
  }
  static __device__ void ld16(const T* __restrict__ p, float* o){
    const uint4* q = reinterpret_cast<const uint4*>(p);
    #pragma unroll
    for (int half = 0; half < 2; ++half){
      uint4 u = q[half];
      o[half*8+0] = bf2f((unsigned short)(u.x & 0xffff));
      o[half*8+1] = bf2f((unsigned short)(u.x >> 16));
      o[half*8+2] = bf2f((unsigned short)(u.y & 0xffff));
      o[half*8+3] = bf2f((unsigned short)(u.y >> 16));
      o[half*8+4] = bf2f((unsigned short)(u.z & 0xffff));
      o[half*8+5] = bf2f((unsigned short)(u.z >> 16));
      o[half*8+6] = bf2f((unsigned short)(u.w & 0xffff));
      o[half*8+7] = bf2f((unsigned short)(u.w >> 16));
    }
  }
};

__global__ void zero_int_kernel(int* __restrict__ p, int n){
  int i = blockIdx.x*256 + threadIdx.x;
  int stride = gridDim.x*256;
  for (; i < n; i += stride) p[i] = 0;
}

__global__ void diag_kernel(float* o, float v){
  if (threadIdx.x == 0 && blockIdx.x == 0) o[0] = v;
}

__global__ void hist_kernel(const int* __restrict__ dst, int* __restrict__ counts, int nE){
  int e = blockIdx.x*256 + threadIdx.x;
  if (e >= nE) return;
  atomicAdd(&counts[dst[e]], 1);
}

// ---- multi-block exclusive scan (3 phases) ----
__global__ void scan_a(const int* __restrict__ counts, int* __restrict__ bsum, int n){
  int base = blockIdx.x*SCAN_TILE;
  int s = 0;
  for (int i = threadIdx.x; i < SCAN_TILE; i += 256){
    int g = base + i;
    s += (g < n) ? counts[g] : 0;
  }
  __shared__ int red[256];
  red[threadIdx.x] = s;
  __syncthreads();
  for (int off = 128; off > 0; off >>= 1){
    if (threadIdx.x < off) red[threadIdx.x] += red[threadIdx.x + off];
    __syncthreads();
  }
  if (threadIdx.x == 0) bsum[blockIdx.x] = red[0];
}

__global__ void scan_b(int* __restrict__ bsum, int nb){
  __shared__ int sh[1024];
  int t = threadIdx.x;
  int v = (t < nb) ? bsum[t] : 0;
  sh[t] = v;
  __syncthreads();
  for (int off = 1; off < 1024; off <<= 1){
    int add = (t >= off) ? sh[t-off] : 0;
    __syncthreads();
    sh[t] += add;
    __syncthreads();
  }
  if (t < nb) bsum[t] = sh[t] - v;   // exclusive
}

__global__ void scan_c(int* __restrict__ counts, const int* __restrict__ bsum,
                       int* __restrict__ rp, int n){
  int base = blockIdx.x*SCAN_TILE;
  __shared__ int sh[SCAN_TILE];
  for (int i = threadIdx.x; i < SCAN_TILE; i += 256){
    int g = base + i;
    sh[i] = (g < n) ? counts[g] : 0;
  }
  __syncthreads();
  int t = threadIdx.x;
  int loc[8], s = 0;
  #pragma unroll
  for (int i = 0; i < 8; ++i){ loc[i] = s; s += sh[t*8 + i]; }
  __shared__ int red[256];
  red[t] = s;
  __syncthreads();
  for (int off = 1; off < 256; off <<= 1){
    int add = (t >= off) ? red[t-off] : 0;
    __syncthreads();
    red[t] += add;
    __syncthreads();
  }
  int texcl = red[t] - s + bsum[blockIdx.x];
  #pragma unroll
  for (int i = 0; i < 8; ++i){
    int g = base + t*8 + i;
    if (g < n){
      int v = texcl + loc[i];
      rp[g] = v;
      counts[g] = v;           // cursor for fill pass
      if (g == n-1) rp[n] = v + sh[t*8 + i];
    }
  }
}

__global__ void fill_slots_kernel(const int* __restrict__ src, const int* __restrict__ dst,
                                  int* __restrict__ cursor, int* __restrict__ slots, int nE){
  int e = blockIdx.x*256 + threadIdx.x;
  if (e >= nE) return;
  int slot = atomicAdd(&cursor[dst[e]], 1);
  slots[slot] = src[e];
}

// Fold rel_a/rel_m into K/V projection weights (fp32).
__global__ void eff_w_kernel(const float* __restrict__ kqv_w, const float* __restrict__ kqv_b,
                             const float* __restrict__ rel_a, const float* __restrict__ rel_m,
                             float* __restrict__ effw, float* __restrict__ effb){
  int idx = blockIdx.x*256 + threadIdx.x;
  if (idx >= 2*2*2*128*128) return;
  int j = idx & 127; int f = (idx >> 7) & 127; int c = idx >> 14;
  int kv = c & 1, t = (c >> 1) & 1, l = c >> 2;
  int h = j >> 4, e2 = j & 15;
  int i = (kv == 0) ? 0 : 2;  // K uses i=0, V uses i=2
  const float* W = kqv_w + ((size_t)(((l*2 + t)*3 + i)*128) + f)*128 + h*16;
  const float* A = ((kv == 0) ? rel_a : rel_m) + ((size_t)(l*2 + t)*8 + h)*256;
  float acc = 0.f;
  #pragma unroll
  for (int d = 0; d < 16; ++d) acc += W[d]*A[d*16 + e2];
  effw[(size_t)c*16384 + f*128 + j] = acc;
  if (f == 0){
    const float* B = kqv_b + (size_t)((l*2 + t)*3 + i)*128 + h*16;
    float ab = 0.f;
    #pragma unroll
    for (int d = 0; d < 16; ++d) ab += B[d]*A[d*16 + e2];
    effb[c*128 + j] = ab;
  }
}

// Convert 19 weight matrices fp32 [k][n] -> bf16 transposed [n][128(k)].
struct PrepSrc { const float* s[19]; };
__global__ void prep_w_kernel(PrepSrc P, unsigned short* __restrict__ wbf){
  int idx = blockIdx.x*256 + threadIdx.x;
  if (idx >= 19*16384) return;
  int s = idx >> 14, j = idx & 16383;
  int n = j >> 7, k = j & 127;
  int nc = (s == 18) ? 64 : 128;
  if (n >= nc) return;
  wbf[(size_t)s*16384 + n*128 + k] = f2bf(P.s[s][(size_t)k*nc + n]);
}

// MFMA GEMM: Y[N,BN] = epi( act(X[N,128]) @ W[128,BN] + bias ).
// A tile in LDS (XOR-swizzled); B fragments loaded directly from global (L1/L2-resident).
template<int BN, int GELU_IN, int RELU_OUT, int SKIP, typename SIn, typename SOut>
__global__ __launch_bounds__(256) void gemm_kernel(
    const typename SIn::T* __restrict__ X,
    const unsigned short* __restrict__ WT,
    const float* __restrict__ bias,
    typename SOut::T* __restrict__ Y, int N,
    const typename SOut::T* __restrict__ skip_x,
    const float* __restrict__ skip_s)
{
  __shared__ __align__(16) short As[128*128];
  const int t = threadIdx.x;
  const int row0 = blockIdx.x*128;
  for (int c = t; c < 128*16; c += 256){
    int r = c >> 4, c16 = c & 15;
    int gr = row0 + r;
    short8v v;
    if (gr < N){
      v = SIn::ld8(&X[(size_t)gr*128 + c16*8]);
      if (GELU_IN){
        #pragma unroll
        for (int i = 0; i < 8; ++i){
          float f = geluf(bf2f((unsigned short)v[i]));
          v[i] = (short)f2bf(f);
        }
      }
    } else {
      v = (short8v)0;
    }
    *reinterpret_cast<short8v*>(&As[r*128 + ((c16 ^ (r&7))<<3)]) = v;
  }
  __syncthreads();
  const int lane = t & 63, wid = t >> 6;
  const int wm = wid >> 1, wn = wid & 1;
  constexpr int NR = BN/32;
  const int lr = lane & 15, lk = lane >> 4;
  f32x4 acc[4][NR] = {};
  #pragma unroll
  for (int kk = 0; kk < 4; ++kk){
    int kc = kk*4 + lk;
    short8v a[4], b[NR];
    #pragma unroll
    for (int m = 0; m < 4; ++m){
      int r = wm*64 + m*16 + lr;
      a[m] = *reinterpret_cast<const short8v*>(&As[r*128 + ((kc ^ (r&7))<<3)]);
    }
    #pragma unroll
    for (int n = 0; n < NR; ++n){
      int col = wn*(BN/2) + n*16 + lr;
      b[n] = *reinterpret_cast<const short8v*>(&WT[(size_t)col*128 + kc*8]);
    }
    #pragma unroll
    for (int m = 0; m < 4; ++m)
      #pragma unroll
      for (int n = 0; n < NR; ++n)
        acc[m][n] = __builtin_amdgcn_mfma_f32_16x16x32_bf16(a[m], b[n], acc[m][n], 0, 0, 0);
  }
  float g = 1.f, og = 0.f;
  if (SKIP){ float sv = *skip_s; g = 1.f/(1.f + expf(-sv)); og = 1.f - g; }
  #pragma unroll
  for (int m = 0; m < 4; ++m){
    #pragma unroll
    for (int r = 0; r < 4; ++r){
      int row = row0 + wm*64 + m*16 + lk*4 + r;
      if (row >= N) continue;
      #pragma unroll
      for (int n = 0; n < NR; ++n){
        int col = wn*(BN/2) + n*16 + lr;
        float y = acc[m][n][r] + bias[col];
        if (RELU_OUT) y = fmaxf(y, 0.f);
        if (SKIP) y = g*y + og*SOut::ld(&skip_x[(size_t)row*BN + col]);
        SOut::st(&Y[(size_t)row*BN + col], y);
      }
    }
  }
}

// Fused QKV: stage X tile once, 3 weight GEMMs back-to-back (B from global), write Q/K/V.
__global__ __launch_bounds__(256) void qkv_kernel(
    const unsigned short* __restrict__ X,
    const unsigned short* __restrict__ WTq,
    const unsigned short* __restrict__ WTk,
    const unsigned short* __restrict__ WTv,
    const float* __restrict__ bq, const float* __restrict__ bk, const float* __restrict__ bv,
    unsigned short* __restrict__ Q, unsigned short* __restrict__ K, unsigned short* __restrict__ V,
    int N)
{
  __shared__ __align__(16) short As[128*128];
  const int t = threadIdx.x;
  const int row0 = blockIdx.x*128;
  for (int c = t; c < 128*16; c += 256){
    int r = c >> 4, c16 = c & 15;
    int gr = row0 + r;
    short8v v = (gr < N) ? *reinterpret_cast<const short8v*>(&X[(size_t)gr*128 + c16*8])
                         : (short8v)0;
    *reinterpret_cast<short8v*>(&As[r*128 + ((c16 ^ (r&7))<<3)]) = v;
  }
  __syncthreads();
  const int lane = t & 63, wid = t >> 6;
  const int wm = wid >> 1, wn = wid & 1;
  const int lr = lane & 15, lk = lane >> 4;
  const unsigned short* wts[3] = {WTq, WTk, WTv};
  const float* bias[3] = {bq, bk, bv};
  unsigned short* outs[3] = {Q, K, V};
  #pragma unroll
  for (int s = 0; s < 3; ++s){
    const unsigned short* WT = wts[s];
    f32x4 acc[4][4] = {};
    #pragma unroll
    for (int kk = 0; kk < 4; ++kk){
      int kc = kk*4 + lk;
      short8v a[4], b[4];
      #pragma unroll
      for (int m = 0; m < 4; ++m){
        int r = wm*64 + m*16 + lr;
        a[m] = *reinterpret_cast<const short8v*>(&As[r*128 + ((kc ^ (r&7))<<3)]);
      }
      #pragma unroll
      for (int n = 0; n < 4; ++n){
        int col = wn*64 + n*16 + lr;
        b[n] = *reinterpret_cast<const short8v*>(&WT[(size_t)col*128 + kc*8]);
      }
      #pragma unroll
      for (int m = 0; m < 4; ++m)
        #pragma unroll
        for (int n = 0; n < 4; ++n)
          acc[m][n] = __builtin_amdgcn_mfma_f32_16x16x32_bf16(a[m], b[n], acc[m][n], 0, 0, 0);
    }
    const float* bi = bias[s];
    unsigned short* out = outs[s];
    #pragma unroll
    for (int m = 0; m < 4; ++m){
      #pragma unroll
      for (int r = 0; r < 4; ++r){
        int row = row0 + wm*64 + m*16 + lk*4 + r;
        if (row >= N) continue;
        #pragma unroll
        for (int n = 0; n < 4; ++n){
          int col = wn*64 + n*16 + lr;
          out[(size_t)row*128 + col] = f2bf(acc[m][n][r] + bi[col]);
        }
      }
    }
  }
}

// Fused attention: one thread per (dst node, head). Online softmax over CSR in-edges.
__global__ void attn_gather_kernel(unsigned short* __restrict__ QA,
                                   const unsigned short* __restrict__ K,
                                   const unsigned short* __restrict__ V,
                                   const int* __restrict__ rp, const int* __restrict__ slots,
                                   const float* __restrict__ relp, int N){
  int idx = blockIdx.x*256 + threadIdx.x;
  if (idx >= N*8) return;
  int h = idx & 7, n = idx >> 3;
  float q[16];
  StBF16::ld16(&QA[(size_t)n*128 + h*16], q);
  float scale_h = relp[h]*0.25f;
  float m = -INFINITY, s = 0.f, acc[16];
  #pragma unroll
  for (int i = 0; i < 16; ++i) acc[i] = 0.f;
  int b = rp[n], e = rp[n+1];
  for (int j = b; j < e; ++j){
    int sv = slots[j];
    float kf[16], vf[16];
    StBF16::ld16(&K[(size_t)sv*128 + h*16], kf);
    float a = 0.f;
    #pragma unroll
    for (int i = 0; i < 16; ++i) a += q[i]*kf[i];
    a *= scale_h;
    float mn = fmaxf(m, a);
    float c = expf(m - mn);
    float p = expf(a - mn);
    StBF16::ld16(&V[(size_t)sv*128 + h*16], vf);
    s = s*c + p;
    #pragma unroll
    for (int i = 0; i < 16; ++i) acc[i] = acc[i]*c + p*vf[i];
    m = mn;
  }
  float inv = 1.f/(s + 1e-16f);
  #pragma unroll
  for (int i = 0; i < 16; ++i) QA[(size_t)n*128 + h*16 + i] = f2bf(acc[i]*inv);
}

struct Ptrs {
  const float *x_author, *x_paper, *win_w, *win_b, *kqv_w, *kqv_b, *a_w, *a_b;
  const float *skip, *rel_a, *rel_m, *rel_p, *out_w, *out_b;
  const int *src0, *dst0, *src1, *dst1;
};

static void run_pipeline(const Ptrs& P, float* d_out, char* ws, hipStream_t stream){
  using BF = unsigned short;
  size_t off = 0;
  auto alloc = [&](size_t bytes) -> void* {
    void* p = ws + off;
    off += (bytes + 255) & ~(size_t)255;
    return p;
  };
  BF* X0 = (BF*)alloc((size_t)Na*128*2);
  BF* X1 = (BF*)alloc((size_t)Np*128*2);
  BF* Q0 = (BF*)alloc((size_t)Na*128*2);   // Q -> agg in place
  BF* Q1 = (BF*)alloc((size_t)Np*128*2);
  BF* K0 = (BF*)alloc((size_t)Na*128*2);
  BF* K1 = (BF*)alloc((size_t)Np*128*2);
  BF* V0 = (BF*)alloc((size_t)Na*128*2);
  BF* V1 = (BF*)alloc((size_t)Np*128*2);
  float* effw = (float*)alloc((size_t)8*16384*4);
  float* effb = (float*)alloc((size_t)8*128*4);
  BF* wbf = (BF*)alloc((size_t)19*16384*2);
  int* rp0   = (int*)alloc((size_t)(Np+1)*4);
  int* cur0  = (int*)alloc((size_t)Np*4);
  int* slot0 = (int*)alloc((size_t)E*4);
  int* rp1   = (int*)alloc((size_t)(Na+1)*4);
  int* cur1  = (int*)alloc((size_t)Na*4);
  int* slot1 = (int*)alloc((size_t)E*4);
  int* bsum  = (int*)alloc((size_t)1024*4);

  auto cdiv = [](int a, int b){ return (a+b-1)/b; };
  const int geE = cdiv(E, 256);
  const int ga = cdiv(Na, 128), gp = cdiv(Np, 128);
  const int sb0 = cdiv(Np, SCAN_TILE), sb1 = cdiv(Na, SCAN_TILE);

  eff_w_kernel<<<512, 256, 0, stream>>>(P.kqv_w, P.kqv_b, P.rel_a, P.rel_m, effw, effb);

  // weight prep: slots 0-1 win, 2-5 Q(l,t), 6-9 K, 10-13 V, 14-17 a_w, 18 out_w
  PrepSrc ps;
  ps.s[0] = P.win_w; ps.s[1] = P.win_w + 16384;
  for (int l = 0; l < 2; ++l)
    for (int t = 0; t < 2; ++t){
      ps.s[2 + l*2 + t]  = P.kqv_w + (size_t)((l*2+t)*3+1)*16384;
      ps.s[6 + l*2 + t]  = effw + (size_t)(l*4+t*2+0)*16384;
      ps.s[10 + l*2 + t] = effw + (size_t)(l*4+t*2+1)*16384;
      ps.s[14 + l*2 + t] = P.a_w + (size_t)(l*2+t)*16384;
    }
  ps.s[18] = P.out_w;
  prep_w_kernel<<<cdiv(19*16384,256),256,0,stream>>>(ps, wbf);

  // ---- CSR build ----
  zero_int_kernel<<<512,256,0,stream>>>(cur0, Np);
  zero_int_kernel<<<512,256,0,stream>>>(cur1, Na);
  hist_kernel<<<geE,256,0,stream>>>(P.dst0, cur0, E);
  hist_kernel<<<geE,256,0,stream>>>(P.dst1, cur1, E);
  scan_a<<<sb0,256,0,stream>>>(cur0, bsum, Np);
  scan_b<<<1,1024,0,stream>>>(bsum, sb0);
  scan_c<<<sb0,256,0,stream>>>(cur0, bsum, rp0, Np);
  scan_a<<<sb1,256,0,stream>>>(cur1, bsum, Na);
  scan_b<<<1,1024,0,stream>>>(bsum, sb1);
  scan_c<<<sb1,256,0,stream>>>(cur1, bsum, rp1, Na);
  fill_slots_kernel<<<geE,256,0,stream>>>(P.src0, P.dst0, cur0, slot0, E);
  fill_slots_kernel<<<geE,256,0,stream>>>(P.src1, P.dst1, cur1, slot1, E);

  auto W = [&](int s){ return wbf + (size_t)s*16384; };

  // input projections + relu (fp32 in, bf16 out)
  gemm_kernel<128,0,1,0,StF32,StBF16><<<ga,256,0,stream>>>(P.x_author, W(0), P.win_b,     X0, Na, nullptr, nullptr);
  gemm_kernel<128,0,1,0,StF32,StBF16><<<gp,256,0,stream>>>(P.x_paper,  W(1), P.win_b+128, X1, Np, nullptr, nullptr);

  for (int l = 0; l < L; ++l){
    qkv_kernel<<<ga,256,0,stream>>>(X0, W(2+l*2+0), W(6+l*2+0), W(10+l*2+0),
                                    P.kqv_b + ((l*2+0)*3+1)*128, effb + (l*4+0)*128, effb + (l*4+1)*128,
                                    Q0, K0, V0, Na);
    qkv_kernel<<<gp,256,0,stream>>>(X1, W(2+l*2+1), W(6+l*2+1), W(10+l*2+1),
                                    P.kqv_b + ((l*2+1)*3+1)*128, effb + (l*4+2)*128, effb + (l*4+3)*128,
                                    Q1, K1, V1, Np);
    attn_gather_kernel<<<cdiv(Np*8,256),256,0,stream>>>(Q1, K0, V0, rp0, slot0, P.rel_p + (l*2+0)*8, Np);
    attn_gather_kernel<<<cdiv(Na*8,256),256,0,stream>>>(Q0, K1, V1, rp1, slot1, P.rel_p + (l*2+1)*8, Na);
    gemm_kernel<128,1,0,1,StBF16,StBF16><<<ga,256,0,stream>>>(Q0, W(14+l*2+0), P.a_b + (l*2+0)*128, X0, Na, X0, P.skip + (l*2+0));
    gemm_kernel<128,1,0,1,StBF16,StBF16><<<gp,256,0,stream>>>(Q1, W(14+l*2+1), P.a_b + (l*2+1)*128, X1, Np, X1, P.skip + (l*2+1));
  }

  gemm_kernel<64,0,0,0,StBF16,StF32><<<ga,256,0,stream>>>(X0, W(18), P.out_b, d_out, Na, nullptr, nullptr);
}

static size_t plan_bytes(){
  auto al = [](size_t x){ return (x + 255) & ~(size_t)255; };
  size_t t = 0;
  t += 4*(al((size_t)Na*128*2) + al((size_t)Np*128*2));   // X,Q,K,V bf16
  t += al((size_t)8*16384*4) + al((size_t)8*128*4) + al((size_t)19*16384*2);
  t += al((size_t)(Np+1)*4) + al((size_t)Np*4) + al((size_t)E*4);
  t += al((size_t)(Na+1)*4) + al((size_t)Na*4) + al((size_t)E*4);
  t += al((size_t)1024*4);
  return t;
}

} // namespace

extern "C" void kernel_launch(void* const* d_in, const int* in_sizes, int n_in,
                              void* d_out, int out_size, void* d_ws, size_t ws_size,
                              hipStream_t stream){
  Ptrs P;
  P.x_author = (const float*)d_in[0];
  P.x_paper  = (const float*)d_in[1];
  P.win_w = (const float*)d_in[2];
  P.win_b = (const float*)d_in[3];
  P.kqv_w = (const float*)d_in[4];
  P.kqv_b = (const float*)d_in[5];
  P.a_w   = (const float*)d_in[6];
  P.a_b   = (const float*)d_in[7];
  P.skip  = (const float*)d_in[8];
  P.rel_a = (const float*)d_in[9];
  P.rel_m = (const float*)d_in[10];
  P.rel_p = (const float*)d_in[11];
  P.out_w = (const float*)d_in[12];
  P.out_b = (const float*)d_in[13];
  P.src0 = (const int*)d_in[14];
  P.dst0 = (const int*)d_in[15];
  P.src1 = (const int*)d_in[16];
  P.dst1 = (const int*)d_in[17];

  if (ws_size >= plan_bytes()){
    run_pipeline(P, (float*)d_out, (char*)d_ws, stream);
  } else {
    diag_kernel<<<1,1,0,stream>>>((float*)d_out, (float)((double)ws_size/1.0e6));
  }
}

// Round 9
// 394.748 us; speedup vs baseline: 1.1944x; 1.1944x over previous
//
#include <hip/hip_runtime.h>
#include <math.h>

namespace {

constexpr int Na = 50000, Np = 100000, L = 2, E = 150000;
constexpr int SCAN_TILE = 2048;

typedef __attribute__((ext_vector_type(8))) short short8v;
typedef __attribute__((ext_vector_type(4))) float f32x4;

__device__ inline float geluf(float x){ return 0.5f*x*(1.0f + erff(x*0.7071067811865476f)); }

__device__ inline float bf2f(unsigned short u){ return __uint_as_float(((unsigned)u) << 16); }
__device__ inline unsigned short f2bf(float f){
  unsigned u = __float_as_uint(f);
  u += 0x7FFFu + ((u >> 16) & 1u);   // round-to-nearest-even
  return (unsigned short)(u >> 16);
}
__device__ inline unsigned pk2(float a, float b){
  return (unsigned)f2bf(a) | ((unsigned)f2bf(b) << 16);
}

struct StF32 {
  using T = float;
  static __device__ float ld(const T* p){ return *p; }
  static __device__ short8v ld8(const T* __restrict__ p){
    float4 lo = *reinterpret_cast<const float4*>(p);
    float4 hi = *reinterpret_cast<const float4*>(p+4);
    short8v v;
    v[0]=(short)f2bf(lo.x); v[1]=(short)f2bf(lo.y); v[2]=(short)f2bf(lo.z); v[3]=(short)f2bf(lo.w);
    v[4]=(short)f2bf(hi.x); v[5]=(short)f2bf(hi.y); v[6]=(short)f2bf(hi.z); v[7]=(short)f2bf(hi.w);
    return v;
  }
};
struct StBF16 {
  using T = unsigned short;
  static __device__ float ld(const T* p){ return bf2f(*p); }
  static __device__ short8v ld8(const T* __restrict__ p){
    return *reinterpret_cast<const short8v*>(p);
  }
  static __device__ void ld16(const T* __restrict__ p, float* o){
    const uint4* q = reinterpret_cast<const uint4*>(p);
    #pragma unroll
    for (int half = 0; half < 2; ++half){
      uint4 u = q[half];
      o[half*8+0] = bf2f((unsigned short)(u.x & 0xffff));
      o[half*8+1] = bf2f((unsigned short)(u.x >> 16));
      o[half*8+2] = bf2f((unsigned short)(u.y & 0xffff));
      o[half*8+3] = bf2f((unsigned short)(u.y >> 16));
      o[half*8+4] = bf2f((unsigned short)(u.z & 0xffff));
      o[half*8+5] = bf2f((unsigned short)(u.z >> 16));
      o[half*8+6] = bf2f((unsigned short)(u.w & 0xffff));
      o[half*8+7] = bf2f((unsigned short)(u.w >> 16));
    }
  }
};

__global__ void zero_int_kernel(int* __restrict__ p, int n){
  int i = blockIdx.x*256 + threadIdx.x;
  int stride = gridDim.x*256;
  for (; i < n; i += stride) p[i] = 0;
}

__global__ void diag_kernel(float* o, float v){
  if (threadIdx.x == 0 && blockIdx.x == 0) o[0] = v;
}

__global__ void hist_kernel(const int* __restrict__ dst, int* __restrict__ counts, int nE){
  int e = blockIdx.x*256 + threadIdx.x;
  if (e >= nE) return;
  atomicAdd(&counts[dst[e]], 1);
}

// ---- multi-block exclusive scan (3 phases) ----
__global__ void scan_a(const int* __restrict__ counts, int* __restrict__ bsum, int n){
  int base = blockIdx.x*SCAN_TILE;
  int s = 0;
  for (int i = threadIdx.x; i < SCAN_TILE; i += 256){
    int g = base + i;
    s += (g < n) ? counts[g] : 0;
  }
  __shared__ int red[256];
  red[threadIdx.x] = s;
  __syncthreads();
  for (int off = 128; off > 0; off >>= 1){
    if (threadIdx.x < off) red[threadIdx.x] += red[threadIdx.x + off];
    __syncthreads();
  }
  if (threadIdx.x == 0) bsum[blockIdx.x] = red[0];
}

__global__ void scan_b(int* __restrict__ bsum, int nb){
  __shared__ int sh[1024];
  int t = threadIdx.x;
  int v = (t < nb) ? bsum[t] : 0;
  sh[t] = v;
  __syncthreads();
  for (int off = 1; off < 1024; off <<= 1){
    int add = (t >= off) ? sh[t-off] : 0;
    __syncthreads();
    sh[t] += add;
    __syncthreads();
  }
  if (t < nb) bsum[t] = sh[t] - v;   // exclusive
}

__global__ void scan_c(int* __restrict__ counts, const int* __restrict__ bsum,
                       int* __restrict__ rp, int n){
  int base = blockIdx.x*SCAN_TILE;
  __shared__ int sh[SCAN_TILE];
  for (int i = threadIdx.x; i < SCAN_TILE; i += 256){
    int g = base + i;
    sh[i] = (g < n) ? counts[g] : 0;
  }
  __syncthreads();
  int t = threadIdx.x;
  int loc[8], s = 0;
  #pragma unroll
  for (int i = 0; i < 8; ++i){ loc[i] = s; s += sh[t*8 + i]; }
  __shared__ int red[256];
  red[t] = s;
  __syncthreads();
  for (int off = 1; off < 256; off <<= 1){
    int add = (t >= off) ? red[t-off] : 0;
    __syncthreads();
    red[t] += add;
    __syncthreads();
  }
  int texcl = red[t] - s + bsum[blockIdx.x];
  #pragma unroll
  for (int i = 0; i < 8; ++i){
    int g = base + t*8 + i;
    if (g < n){
      int v = texcl + loc[i];
      rp[g] = v;
      counts[g] = v;           // cursor for fill pass
      if (g == n-1) rp[n] = v + sh[t*8 + i];
    }
  }
}

__global__ void fill_slots_kernel(const int* __restrict__ src, const int* __restrict__ dst,
                                  int* __restrict__ cursor, int* __restrict__ slots, int nE){
  int e = blockIdx.x*256 + threadIdx.x;
  if (e >= nE) return;
  int slot = atomicAdd(&cursor[dst[e]], 1);
  slots[slot] = src[e];
}

// Fold rel_a/rel_m into K/V projection weights (fp32).
__global__ void eff_w_kernel(const float* __restrict__ kqv_w, const float* __restrict__ kqv_b,
                             const float* __restrict__ rel_a, const float* __restrict__ rel_m,
                             float* __restrict__ effw, float* __restrict__ effb){
  int idx = blockIdx.x*256 + threadIdx.x;
  if (idx >= 2*2*2*128*128) return;
  int j = idx & 127; int f = (idx >> 7) & 127; int c = idx >> 14;
  int kv = c & 1, t = (c >> 1) & 1, l = c >> 2;
  int h = j >> 4, e2 = j & 15;
  int i = (kv == 0) ? 0 : 2;  // K uses i=0, V uses i=2
  const float* W = kqv_w + ((size_t)(((l*2 + t)*3 + i)*128) + f)*128 + h*16;
  const float* A = ((kv == 0) ? rel_a : rel_m) + ((size_t)(l*2 + t)*8 + h)*256;
  float acc = 0.f;
  #pragma unroll
  for (int d = 0; d < 16; ++d) acc += W[d]*A[d*16 + e2];
  effw[(size_t)c*16384 + f*128 + j] = acc;
  if (f == 0){
    const float* B = kqv_b + (size_t)((l*2 + t)*3 + i)*128 + h*16;
    float ab = 0.f;
    #pragma unroll
    for (int d = 0; d < 16; ++d) ab += B[d]*A[d*16 + e2];
    effb[c*128 + j] = ab;
  }
}

// Convert 19 weight matrices fp32 [k][n] -> bf16 transposed [n][128(k)].
struct PrepSrc { const float* s[19]; };
__global__ void prep_w_kernel(PrepSrc P, unsigned short* __restrict__ wbf){
  int idx = blockIdx.x*256 + threadIdx.x;
  if (idx >= 19*16384) return;
  int s = idx >> 14, j = idx & 16383;
  int n = j >> 7, k = j & 127;
  int nc = (s == 18) ? 64 : 128;
  if (n >= nc) return;
  wbf[(size_t)s*16384 + n*128 + k] = f2bf(P.s[s][(size_t)k*nc + n]);
}

// Stage bf16 WT [rows][128] into LDS with 16B-chunk XOR swizzle.
__device__ inline void stage_w(short* Bs, const unsigned short* __restrict__ WT, int t, int rows){
  for (int c = t; c < rows*16; c += 256){
    int r = c >> 4, c16 = c & 15;
    short8v v = *reinterpret_cast<const short8v*>(&WT[r*128 + c16*8]);
    *reinterpret_cast<short8v*>(&Bs[r*128 + ((c16 ^ (r&7))<<3)]) = v;
  }
}

// MFMA GEMM: Y[N,BN] = epi( act(X[N,128]) @ W[128,BN] + bias ).
// Swapped-operand MFMA -> lane holds 4 consecutive output cols of one row.
// Repack through LDS (reusing Bs) -> fully coalesced 16B stores.
// BN=128: bf16 out (+optional gated skip); BN=64: fp32 out (classifier).
template<int BN, int GELU_IN, int RELU_OUT, int SKIP, typename SIn>
__global__ __launch_bounds__(256) void gemm_kernel(
    const typename SIn::T* __restrict__ X,
    const unsigned short* __restrict__ WT,
    const float* __restrict__ bias,
    void* __restrict__ Y, int N,
    const unsigned short* __restrict__ skip_x,
    const float* __restrict__ skip_s)
{
  __shared__ __align__(16) short As[128*128];
  __shared__ __align__(16) char Braw[32768];
  short* Bs = (short*)Braw;
  const int t = threadIdx.x;
  const int row0 = blockIdx.x*128;
  for (int c = t; c < 128*16; c += 256){
    int r = c >> 4, c16 = c & 15;
    int gr = row0 + r;
    short8v v;
    if (gr < N){
      v = SIn::ld8(&X[(size_t)gr*128 + c16*8]);
      if (GELU_IN){
        #pragma unroll
        for (int i = 0; i < 8; ++i){
          float f = geluf(bf2f((unsigned short)v[i]));
          v[i] = (short)f2bf(f);
        }
      }
    } else {
      v = (short8v)0;
    }
    *reinterpret_cast<short8v*>(&As[r*128 + ((c16 ^ (r&7))<<3)]) = v;
  }
  stage_w(Bs, WT, t, BN);
  __syncthreads();
  const int lane = t & 63, wid = t >> 6;
  const int wm = wid >> 1, wn = wid & 1;
  constexpr int NR = BN/32;
  const int lr = lane & 15, lk = lane >> 4;
  f32x4 acc[4][NR] = {};
  #pragma unroll
  for (int kk = 0; kk < 4; ++kk){
    int kc = kk*4 + lk;
    short8v a[4], b[NR];
    #pragma unroll
    for (int m = 0; m < 4; ++m){
      int r = wm*64 + m*16 + lr;
      a[m] = *reinterpret_cast<const short8v*>(&As[r*128 + ((kc ^ (r&7))<<3)]);
    }
    #pragma unroll
    for (int n = 0; n < NR; ++n){
      int col = wn*(BN/2) + n*16 + lr;
      b[n] = *reinterpret_cast<const short8v*>(&Bs[col*128 + ((kc ^ (col&7))<<3)]);
    }
    #pragma unroll
    for (int m = 0; m < 4; ++m)
      #pragma unroll
      for (int n = 0; n < NR; ++n)
        acc[m][n] = __builtin_amdgcn_mfma_f32_16x16x32_bf16(b[n], a[m], acc[m][n], 0, 0, 0);
  }
  __syncthreads();   // Bs weight reads done -> reuse as repack buffer

  if constexpr (BN == 128){
    // repack: acc[m][n] = Y[row=wm*64+m*16+lr][cols=wn*64+n*16+lk*4 .. +3]
    #pragma unroll
    for (int m = 0; m < 4; ++m){
      int row = wm*64 + m*16 + lr;
      #pragma unroll
      for (int n = 0; n < NR; ++n){
        int col0 = wn*64 + n*16 + lk*4;
        float4 b4 = *reinterpret_cast<const float4*>(&bias[col0]);
        float y0 = acc[m][n][0] + b4.x, y1 = acc[m][n][1] + b4.y;
        float y2 = acc[m][n][2] + b4.z, y3 = acc[m][n][3] + b4.w;
        if (RELU_OUT){
          y0 = fmaxf(y0,0.f); y1 = fmaxf(y1,0.f); y2 = fmaxf(y2,0.f); y3 = fmaxf(y3,0.f);
        }
        uint2 pk; pk.x = pk2(y0,y1); pk.y = pk2(y2,y3);
        int c16 = col0 >> 3;
        *reinterpret_cast<uint2*>(&Bs[row*128 + ((c16 ^ (row&7))<<3) + (col0&7)]) = pk;
      }
    }
    __syncthreads();
    float g = 1.f, og = 0.f;
    if (SKIP){ float sv = *skip_s; g = 1.f/(1.f + expf(-sv)); og = 1.f - g; }
    unsigned short* out = (unsigned short*)Y;
    for (int c = t; c < 128*16; c += 256){
      int r = c >> 4, c16 = c & 15;
      int gr = row0 + r;
      if (gr >= N) continue;
      short8v v = *reinterpret_cast<const short8v*>(&Bs[r*128 + ((c16 ^ (r&7))<<3)]);
      if (SKIP){
        short8v s8 = *reinterpret_cast<const short8v*>(&skip_x[(size_t)gr*128 + c16*8]);
        short8v o8;
        #pragma unroll
        for (int i = 0; i < 8; ++i)
          o8[i] = (short)f2bf(g*bf2f((unsigned short)v[i]) + og*bf2f((unsigned short)s8[i]));
        *reinterpret_cast<short8v*>(&out[(size_t)gr*128 + c16*8]) = o8;
      } else {
        *reinterpret_cast<short8v*>(&out[(size_t)gr*128 + c16*8]) = v;
      }
    }
  } else {
    // BN==64: fp32 repack (exactly 32 KB), fp32 coalesced out
    float* Bf = (float*)Braw;
    #pragma unroll
    for (int m = 0; m < 4; ++m){
      int row = wm*64 + m*16 + lr;
      #pragma unroll
      for (int n = 0; n < NR; ++n){
        int col0 = wn*32 + n*16 + lk*4;
        float4 b4 = *reinterpret_cast<const float4*>(&bias[col0]);
        float4 y;
        y.x = acc[m][n][0] + b4.x; y.y = acc[m][n][1] + b4.y;
        y.z = acc[m][n][2] + b4.z; y.w = acc[m][n][3] + b4.w;
        int cf = col0 >> 2;
        *reinterpret_cast<float4*>(&Bf[row*64 + ((cf ^ (row&7))<<2)]) = y;
      }
    }
    __syncthreads();
    float* out = (float*)Y;
    for (int c = t; c < 128*16; c += 256){
      int r = c >> 4, cf = c & 15;
      int gr = row0 + r;
      if (gr >= N) continue;
      float4 v = *reinterpret_cast<const float4*>(&Bf[r*64 + ((cf ^ (r&7))<<2)]);
      *reinterpret_cast<float4*>(&out[(size_t)gr*64 + cf*4]) = v;
    }
  }
}

// Fused QKV: stage X once; per weight: stage B, MFMA (swapped), repack via Bs, coalesced store.
__global__ __launch_bounds__(256) void qkv_kernel(
    const unsigned short* __restrict__ X,
    const unsigned short* __restrict__ WTq,
    const unsigned short* __restrict__ WTk,
    const unsigned short* __restrict__ WTv,
    const float* __restrict__ bq, const float* __restrict__ bk, const float* __restrict__ bv,
    unsigned short* __restrict__ Q, unsigned short* __restrict__ K, unsigned short* __restrict__ V,
    int N)
{
  __shared__ __align__(16) short As[128*128];
  __shared__ __align__(16) short Bs[128*128];
  const int t = threadIdx.x;
  const int row0 = blockIdx.x*128;
  for (int c = t; c < 128*16; c += 256){
    int r = c >> 4, c16 = c & 15;
    int gr = row0 + r;
    short8v v = (gr < N) ? *reinterpret_cast<const short8v*>(&X[(size_t)gr*128 + c16*8])
                         : (short8v)0;
    *reinterpret_cast<short8v*>(&As[r*128 + ((c16 ^ (r&7))<<3)]) = v;
  }
  const int lane = t & 63, wid = t >> 6;
  const int wm = wid >> 1, wn = wid & 1;
  const int lr = lane & 15, lk = lane >> 4;
  const unsigned short* wts[3] = {WTq, WTk, WTv};
  const float* bias[3] = {bq, bk, bv};
  unsigned short* outs[3] = {Q, K, V};
  #pragma unroll
  for (int s = 0; s < 3; ++s){
    __syncthreads();                   // A staged (s=0) / prev readout done
    stage_w(Bs, wts[s], t, 128);
    __syncthreads();
    f32x4 acc[4][4] = {};
    #pragma unroll
    for (int kk = 0; kk < 4; ++kk){
      int kc = kk*4 + lk;
      short8v a[4], b[4];
      #pragma unroll
      for (int m = 0; m < 4; ++m){
        int r = wm*64 + m*16 + lr;
        a[m] = *reinterpret_cast<const short8v*>(&As[r*128 + ((kc ^ (r&7))<<3)]);
      }
      #pragma unroll
      for (int n = 0; n < 4; ++n){
        int col = wn*64 + n*16 + lr;
        b[n] = *reinterpret_cast<const short8v*>(&Bs[col*128 + ((kc ^ (col&7))<<3)]);
      }
      #pragma unroll
      for (int m = 0; m < 4; ++m)
        #pragma unroll
        for (int n = 0; n < 4; ++n)
          acc[m][n] = __builtin_amdgcn_mfma_f32_16x16x32_bf16(b[n], a[m], acc[m][n], 0, 0, 0);
    }
    __syncthreads();                   // weight reads done -> repack into Bs
    const float* bi = bias[s];
    #pragma unroll
    for (int m = 0; m < 4; ++m){
      int row = wm*64 + m*16 + lr;
      #pragma unroll
      for (int n = 0; n < 4; ++n){
        int col0 = wn*64 + n*16 + lk*4;
        float4 b4 = *reinterpret_cast<const float4*>(&bi[col0]);
        uint2 pk;
        pk.x = pk2(acc[m][n][0] + b4.x, acc[m][n][1] + b4.y);
        pk.y = pk2(acc[m][n][2] + b4.z, acc[m][n][3] + b4.w);
        int c16 = col0 >> 3;
        *reinterpret_cast<uint2*>(&Bs[row*128 + ((c16 ^ (row&7))<<3) + (col0&7)]) = pk;
      }
    }
    __syncthreads();
    unsigned short* out = outs[s];
    for (int c = t; c < 128*16; c += 256){
      int r = c >> 4, c16 = c & 15;
      int gr = row0 + r;
      if (gr >= N) continue;
      short8v v = *reinterpret_cast<const short8v*>(&Bs[r*128 + ((c16 ^ (r&7))<<3)]);
      *reinterpret_cast<short8v*>(&out[(size_t)gr*128 + c16*8]) = v;
    }
  }
}

// Fused attention: one thread per (dst node, head). Online softmax over CSR in-edges.
__global__ void attn_gather_kernel(unsigned short* __restrict__ QA,
                                   const unsigned short* __restrict__ K,
                                   const unsigned short* __restrict__ V,
                                   const int* __restrict__ rp, const int* __restrict__ slots,
                                   const float* __restrict__ relp, int N){
  int idx = blockIdx.x*256 + threadIdx.x;
  if (idx >= N*8) return;
  int h = idx & 7, n = idx >> 3;
  float q[16];
  StBF16::ld16(&QA[(size_t)n*128 + h*16], q);
  float scale_h = relp[h]*0.25f;
  float m = -INFINITY, s = 0.f, acc[16];
  #pragma unroll
  for (int i = 0; i < 16; ++i) acc[i] = 0.f;
  int b = rp[n], e = rp[n+1];
  for (int j = b; j < e; ++j){
    int sv = slots[j];
    float kf[16], vf[16];
    StBF16::ld16(&K[(size_t)sv*128 + h*16], kf);
    float a = 0.f;
    #pragma unroll
    for (int i = 0; i < 16; ++i) a += q[i]*kf[i];
    a *= scale_h;
    float mn = fmaxf(m, a);
    float c = expf(m - mn);
    float p = expf(a - mn);
    StBF16::ld16(&V[(size_t)sv*128 + h*16], vf);
    s = s*c + p;
    #pragma unroll
    for (int i = 0; i < 16; ++i) acc[i] = acc[i]*c + p*vf[i];
    m = mn;
  }
  float inv = 1.f/(s + 1e-16f);
  #pragma unroll
  for (int i = 0; i < 16; ++i) QA[(size_t)n*128 + h*16 + i] = f2bf(acc[i]*inv);
}

struct Ptrs {
  const float *x_author, *x_paper, *win_w, *win_b, *kqv_w, *kqv_b, *a_w, *a_b;
  const float *skip, *rel_a, *rel_m, *rel_p, *out_w, *out_b;
  const int *src0, *dst0, *src1, *dst1;
};

static void run_pipeline(const Ptrs& P, float* d_out, char* ws, hipStream_t stream){
  using BF = unsigned short;
  size_t off = 0;
  auto alloc = [&](size_t bytes) -> void* {
    void* p = ws + off;
    off += (bytes + 255) & ~(size_t)255;
    return p;
  };
  BF* X0 = (BF*)alloc((size_t)Na*128*2);
  BF* X1 = (BF*)alloc((size_t)Np*128*2);
  BF* Q0 = (BF*)alloc((size_t)Na*128*2);   // Q -> agg in place
  BF* Q1 = (BF*)alloc((size_t)Np*128*2);
  BF* K0 = (BF*)alloc((size_t)Na*128*2);
  BF* K1 = (BF*)alloc((size_t)Np*128*2);
  BF* V0 = (BF*)alloc((size_t)Na*128*2);
  BF* V1 = (BF*)alloc((size_t)Np*128*2);
  float* effw = (float*)alloc((size_t)8*16384*4);
  float* effb = (float*)alloc((size_t)8*128*4);
  BF* wbf = (BF*)alloc((size_t)19*16384*2);
  int* rp0   = (int*)alloc((size_t)(Np+1)*4);
  int* cur0  = (int*)alloc((size_t)Np*4);
  int* slot0 = (int*)alloc((size_t)E*4);
  int* rp1   = (int*)alloc((size_t)(Na+1)*4);
  int* cur1  = (int*)alloc((size_t)Na*4);
  int* slot1 = (int*)alloc((size_t)E*4);
  int* bsum  = (int*)alloc((size_t)1024*4);

  auto cdiv = [](int a, int b){ return (a+b-1)/b; };
  const int geE = cdiv(E, 256);
  const int ga = cdiv(Na, 128), gp = cdiv(Np, 128);
  const int sb0 = cdiv(Np, SCAN_TILE), sb1 = cdiv(Na, SCAN_TILE);

  eff_w_kernel<<<512, 256, 0, stream>>>(P.kqv_w, P.kqv_b, P.rel_a, P.rel_m, effw, effb);

  // weight prep: slots 0-1 win, 2-5 Q(l,t), 6-9 K, 10-13 V, 14-17 a_w, 18 out_w
  PrepSrc ps;
  ps.s[0] = P.win_w; ps.s[1] = P.win_w + 16384;
  for (int l = 0; l < 2; ++l)
    for (int t = 0; t < 2; ++t){
      ps.s[2 + l*2 + t]  = P.kqv_w + (size_t)((l*2+t)*3+1)*16384;
      ps.s[6 + l*2 + t]  = effw + (size_t)(l*4+t*2+0)*16384;
      ps.s[10 + l*2 + t] = effw + (size_t)(l*4+t*2+1)*16384;
      ps.s[14 + l*2 + t] = P.a_w + (size_t)(l*2+t)*16384;
    }
  ps.s[18] = P.out_w;
  prep_w_kernel<<<cdiv(19*16384,256),256,0,stream>>>(ps, wbf);

  // ---- CSR build ----
  zero_int_kernel<<<512,256,0,stream>>>(cur0, Np);
  zero_int_kernel<<<512,256,0,stream>>>(cur1, Na);
  hist_kernel<<<geE,256,0,stream>>>(P.dst0, cur0, E);
  hist_kernel<<<geE,256,0,stream>>>(P.dst1, cur1, E);
  scan_a<<<sb0,256,0,stream>>>(cur0, bsum, Np);
  scan_b<<<1,1024,0,stream>>>(bsum, sb0);
  scan_c<<<sb0,256,0,stream>>>(cur0, bsum, rp0, Np);
  scan_a<<<sb1,256,0,stream>>>(cur1, bsum, Na);
  scan_b<<<1,1024,0,stream>>>(bsum, sb1);
  scan_c<<<sb1,256,0,stream>>>(cur1, bsum, rp1, Na);
  fill_slots_kernel<<<geE,256,0,stream>>>(P.src0, P.dst0, cur0, slot0, E);
  fill_slots_kernel<<<geE,256,0,stream>>>(P.src1, P.dst1, cur1, slot1, E);

  auto W = [&](int s){ return wbf + (size_t)s*16384; };

  // input projections + relu (fp32 in, bf16 out)
  gemm_kernel<128,0,1,0,StF32><<<ga,256,0,stream>>>(P.x_author, W(0), P.win_b,     X0, Na, nullptr, nullptr);
  gemm_kernel<128,0,1,0,StF32><<<gp,256,0,stream>>>(P.x_paper,  W(1), P.win_b+128, X1, Np, nullptr, nullptr);

  for (int l = 0; l < L; ++l){
    qkv_kernel<<<ga,256,0,stream>>>(X0, W(2+l*2+0), W(6+l*2+0), W(10+l*2+0),
                                    P.kqv_b + ((l*2+0)*3+1)*128, effb + (l*4+0)*128, effb + (l*4+1)*128,
                                    Q0, K0, V0, Na);
    qkv_kernel<<<gp,256,0,stream>>>(X1, W(2+l*2+1), W(6+l*2+1), W(10+l*2+1),
                                    P.kqv_b + ((l*2+1)*3+1)*128, effb + (l*4+2)*128, effb + (l*4+3)*128,
                                    Q1, K1, V1, Np);
    attn_gather_kernel<<<cdiv(Np*8,256),256,0,stream>>>(Q1, K0, V0, rp0, slot0, P.rel_p + (l*2+0)*8, Np);
    attn_gather_kernel<<<cdiv(Na*8,256),256,0,stream>>>(Q0, K1, V1, rp1, slot1, P.rel_p + (l*2+1)*8, Na);
    gemm_kernel<128,1,0,1,StBF16><<<ga,256,0,stream>>>(Q0, W(14+l*2+0), P.a_b + (l*2+0)*128, X0, Na, X0, P.skip + (l*2+0));
    gemm_kernel<128,1,0,1,StBF16><<<gp,256,0,stream>>>(Q1, W(14+l*2+1), P.a_b + (l*2+1)*128, X1, Np, X1, P.skip + (l*2+1));
  }

  gemm_kernel<64,0,0,0,StBF16><<<ga,256,0,stream>>>(X0, W(18), P.out_b, d_out, Na, nullptr, nullptr);
}

static size_t plan_bytes(){
  auto al = [](size_t x){ return (x + 255) & ~(size_t)255; };
  size_t t = 0;
  t += 4*(al((size_t)Na*128*2) + al((size_t)Np*128*2));   // X,Q,K,V bf16
  t += al((size_t)8*16384*4) + al((size_t)8*128*4) + al((size_t)19*16384*2);
  t += al((size_t)(Np+1)*4) + al((size_t)Np*4) + al((size_t)E*4);
  t += al((size_t)(Na+1)*4) + al((size_t)Na*4) + al((size_t)E*4);
  t += al((size_t)1024*4);
  return t;
}

} // namespace

extern "C" void kernel_launch(void* const* d_in, const int* in_sizes, int n_in,
                              void* d_out, int out_size, void* d_ws, size_t ws_size,
                              hipStream_t stream){
  Ptrs P;
  P.x_author = (const float*)d_in[0];
  P.x_paper  = (const float*)d_in[1];
  P.win_w = (const float*)d_in[2];
  P.win_b = (const float*)d_in[3];
  P.kqv_w = (const float*)d_in[4];
  P.kqv_b = (const float*)d_in[5];
  P.a_w   = (const float*)d_in[6];
  P.a_b   = (const float*)d_in[7];
  P.skip  = (const float*)d_in[8];
  P.rel_a = (const float*)d_in[9];
  P.rel_m = (const float*)d_in[10];
  P.rel_p = (const float*)d_in[11];
  P.out_w = (const float*)d_in[12];
  P.out_b = (const float*)d_in[13];
  P.src0 = (const int*)d_in[14];
  P.dst0 = (const int*)d_in[15];
  P.src1 = (const int*)d_in[16];
  P.dst1 = (const int*)d_in[17];

  if (ws_size >= plan_bytes()){
    run_pipeline(P, (float*)d_out, (char*)d_ws, stream);
  } else {
    diag_kernel<<<1,1,0,stream>>>((float*)d_out, (float)((double)ws_size/1.0e6));
  }
}

// Round 10
// 336.013 us; speedup vs baseline: 1.4032x; 1.1748x over previous
//
#include <hip/hip_runtime.h>
#include <math.h>

namespace {

constexpr int Na = 50000, Np = 100000, L = 2, E = 150000;
constexpr int SCAN_TILE = 2048;

typedef __attribute__((ext_vector_type(8))) short short8v;
typedef __attribute__((ext_vector_type(4))) float f32x4;

__device__ inline float geluf(float x){ return 0.5f*x*(1.0f + erff(x*0.7071067811865476f)); }

__device__ inline float bf2f(unsigned short u){ return __uint_as_float(((unsigned)u) << 16); }
__device__ inline unsigned short f2bf(float f){
  unsigned u = __float_as_uint(f);
  u += 0x7FFFu + ((u >> 16) & 1u);   // round-to-nearest-even
  return (unsigned short)(u >> 16);
}
__device__ inline unsigned pk2(float a, float b){
  return (unsigned)f2bf(a) | ((unsigned)f2bf(b) << 16);
}

struct StF32 {
  using T = float;
  static __device__ short8v ld8(const T* __restrict__ p){
    float4 lo = *reinterpret_cast<const float4*>(p);
    float4 hi = *reinterpret_cast<const float4*>(p+4);
    short8v v;
    v[0]=(short)f2bf(lo.x); v[1]=(short)f2bf(lo.y); v[2]=(short)f2bf(lo.z); v[3]=(short)f2bf(lo.w);
    v[4]=(short)f2bf(hi.x); v[5]=(short)f2bf(hi.y); v[6]=(short)f2bf(hi.z); v[7]=(short)f2bf(hi.w);
    return v;
  }
};
struct StBF16 {
  using T = unsigned short;
  static __device__ short8v ld8(const T* __restrict__ p){
    return *reinterpret_cast<const short8v*>(p);
  }
  static __device__ void ld16(const T* __restrict__ p, float* o){
    const uint4* q = reinterpret_cast<const uint4*>(p);
    #pragma unroll
    for (int half = 0; half < 2; ++half){
      uint4 u = q[half];
      o[half*8+0] = bf2f((unsigned short)(u.x & 0xffff));
      o[half*8+1] = bf2f((unsigned short)(u.x >> 16));
      o[half*8+2] = bf2f((unsigned short)(u.y & 0xffff));
      o[half*8+3] = bf2f((unsigned short)(u.y >> 16));
      o[half*8+4] = bf2f((unsigned short)(u.z & 0xffff));
      o[half*8+5] = bf2f((unsigned short)(u.z >> 16));
      o[half*8+6] = bf2f((unsigned short)(u.w & 0xffff));
      o[half*8+7] = bf2f((unsigned short)(u.w >> 16));
    }
  }
};

__global__ void zero_int_kernel(int* __restrict__ p, int n){
  int i = blockIdx.x*256 + threadIdx.x;
  int stride = gridDim.x*256;
  for (; i < n; i += stride) p[i] = 0;
}

__global__ void diag_kernel(float* o, float v){
  if (threadIdx.x == 0 && blockIdx.x == 0) o[0] = v;
}

__global__ void hist_kernel(const int* __restrict__ dst, int* __restrict__ counts, int nE){
  int e = blockIdx.x*256 + threadIdx.x;
  if (e >= nE) return;
  atomicAdd(&counts[dst[e]], 1);
}

// ---- multi-block exclusive scan (3 phases) ----
__global__ void scan_a(const int* __restrict__ counts, int* __restrict__ bsum, int n){
  int base = blockIdx.x*SCAN_TILE;
  int s = 0;
  for (int i = threadIdx.x; i < SCAN_TILE; i += 256){
    int g = base + i;
    s += (g < n) ? counts[g] : 0;
  }
  __shared__ int red[256];
  red[threadIdx.x] = s;
  __syncthreads();
  for (int off = 128; off > 0; off >>= 1){
    if (threadIdx.x < off) red[threadIdx.x] += red[threadIdx.x + off];
    __syncthreads();
  }
  if (threadIdx.x == 0) bsum[blockIdx.x] = red[0];
}

__global__ void scan_b(int* __restrict__ bsum, int nb){
  __shared__ int sh[1024];
  int t = threadIdx.x;
  int v = (t < nb) ? bsum[t] : 0;
  sh[t] = v;
  __syncthreads();
  for (int off = 1; off < 1024; off <<= 1){
    int add = (t >= off) ? sh[t-off] : 0;
    __syncthreads();
    sh[t] += add;
    __syncthreads();
  }
  if (t < nb) bsum[t] = sh[t] - v;   // exclusive
}

__global__ void scan_c(int* __restrict__ counts, const int* __restrict__ bsum,
                       int* __restrict__ rp, int n){
  int base = blockIdx.x*SCAN_TILE;
  __shared__ int sh[SCAN_TILE];
  for (int i = threadIdx.x; i < SCAN_TILE; i += 256){
    int g = base + i;
    sh[i] = (g < n) ? counts[g] : 0;
  }
  __syncthreads();
  int t = threadIdx.x;
  int loc[8], s = 0;
  #pragma unroll
  for (int i = 0; i < 8; ++i){ loc[i] = s; s += sh[t*8 + i]; }
  __shared__ int red[256];
  red[t] = s;
  __syncthreads();
  for (int off = 1; off < 256; off <<= 1){
    int add = (t >= off) ? red[t-off] : 0;
    __syncthreads();
    red[t] += add;
    __syncthreads();
  }
  int texcl = red[t] - s + bsum[blockIdx.x];
  #pragma unroll
  for (int i = 0; i < 8; ++i){
    int g = base + t*8 + i;
    if (g < n){
      int v = texcl + loc[i];
      rp[g] = v;
      counts[g] = v;           // cursor for fill pass
      if (g == n-1) rp[n] = v + sh[t*8 + i];
    }
  }
}

__global__ void fill_slots_kernel(const int* __restrict__ src, const int* __restrict__ dst,
                                  int* __restrict__ cursor, int* __restrict__ slots, int nE){
  int e = blockIdx.x*256 + threadIdx.x;
  if (e >= nE) return;
  int slot = atomicAdd(&cursor[dst[e]], 1);
  slots[slot] = src[e];
}

// Fold rel_a/rel_m into K/V projection weights (fp32).
__global__ void eff_w_kernel(const float* __restrict__ kqv_w, const float* __restrict__ kqv_b,
                             const float* __restrict__ rel_a, const float* __restrict__ rel_m,
                             float* __restrict__ effw, float* __restrict__ effb){
  int idx = blockIdx.x*256 + threadIdx.x;
  if (idx >= 2*2*2*128*128) return;
  int j = idx & 127; int f = (idx >> 7) & 127; int c = idx >> 14;
  int kv = c & 1, t = (c >> 1) & 1, l = c >> 2;
  int h = j >> 4, e2 = j & 15;
  int i = (kv == 0) ? 0 : 2;  // K uses i=0, V uses i=2
  const float* W = kqv_w + ((size_t)(((l*2 + t)*3 + i)*128) + f)*128 + h*16;
  const float* A = ((kv == 0) ? rel_a : rel_m) + ((size_t)(l*2 + t)*8 + h)*256;
  float acc = 0.f;
  #pragma unroll
  for (int d = 0; d < 16; ++d) acc += W[d]*A[d*16 + e2];
  effw[(size_t)c*16384 + f*128 + j] = acc;
  if (f == 0){
    const float* B = kqv_b + (size_t)((l*2 + t)*3 + i)*128 + h*16;
    float ab = 0.f;
    #pragma unroll
    for (int d = 0; d < 16; ++d) ab += B[d]*A[d*16 + e2];
    effb[c*128 + j] = ab;
  }
}

// Convert 19 weight matrices fp32 [k][n] -> bf16 transposed [n][128(k)].
struct PrepSrc { const float* s[19]; };
__global__ void prep_w_kernel(PrepSrc P, unsigned short* __restrict__ wbf){
  int idx = blockIdx.x*256 + threadIdx.x;
  if (idx >= 19*16384) return;
  int s = idx >> 14, j = idx & 16383;
  int n = j >> 7, k = j & 127;
  int nc = (s == 18) ? 64 : 128;
  if (n >= nc) return;
  wbf[(size_t)s*16384 + n*128 + k] = f2bf(P.s[s][(size_t)k*nc + n]);
}

// Stage bf16 WT [rows][128] into LDS with 16B-chunk XOR swizzle (512-thread).
__device__ inline void stage_w(short* Bs, const unsigned short* __restrict__ WT, int t, int rows){
  for (int c = t; c < rows*16; c += 512){
    int r = c >> 4, c16 = c & 15;
    short8v v = *reinterpret_cast<const short8v*>(&WT[r*128 + c16*8]);
    *reinterpret_cast<short8v*>(&Bs[r*128 + ((c16 ^ (r&7))<<3)]) = v;
  }
}

struct GemmArgs {
  const void* X[2];
  const unsigned short* WT[2];
  const float* bias[2];
  void* Y[2];
  const unsigned short* skip_x[2];
  const float* skip_s[2];
  int N[2];
  int blocks0;
};

// MFMA GEMM (512 threads, 8 waves 2x4): Y[N,BN] = epi( act(X[N,128]) @ W + bias ).
// Swapped-operand MFMA -> lane holds 4 consecutive output cols; repack via LDS -> 16B stores.
template<int BN, int GELU_IN, int RELU_OUT, int SKIP, typename SIn>
__global__ __launch_bounds__(512) void gemm_kernel(GemmArgs Ar)
{
  __shared__ __align__(16) short As[128*128];
  __shared__ __align__(16) char Braw[32768];
  short* Bs = (short*)Braw;
  const int t = threadIdx.x;
  const int part = (blockIdx.x < Ar.blocks0) ? 0 : 1;
  const int bid = part ? (blockIdx.x - Ar.blocks0) : blockIdx.x;
  const typename SIn::T* X = (const typename SIn::T*)Ar.X[part];
  const unsigned short* WT = Ar.WT[part];
  const float* bias = Ar.bias[part];
  const int N = Ar.N[part];
  const int row0 = bid*128;
  for (int c = t; c < 128*16; c += 512){
    int r = c >> 4, c16 = c & 15;
    int gr = row0 + r;
    short8v v;
    if (gr < N){
      v = SIn::ld8(&X[(size_t)gr*128 + c16*8]);
      if (GELU_IN){
        #pragma unroll
        for (int i = 0; i < 8; ++i){
          float f = geluf(bf2f((unsigned short)v[i]));
          v[i] = (short)f2bf(f);
        }
      }
    } else {
      v = (short8v)0;
    }
    *reinterpret_cast<short8v*>(&As[r*128 + ((c16 ^ (r&7))<<3)]) = v;
  }
  stage_w(Bs, WT, t, BN);
  __syncthreads();
  const int lane = t & 63, wid = t >> 6;
  const int wm = wid >> 2, wn = wid & 3;       // 2 x 4 waves
  constexpr int NR = BN/64;                    // n-frags per wave
  const int lr = lane & 15, lk = lane >> 4;
  f32x4 acc[4][NR] = {};
  #pragma unroll
  for (int kk = 0; kk < 4; ++kk){
    int kc = kk*4 + lk;
    short8v a[4], b[NR];
    #pragma unroll
    for (int m = 0; m < 4; ++m){
      int r = wm*64 + m*16 + lr;
      a[m] = *reinterpret_cast<const short8v*>(&As[r*128 + ((kc ^ (r&7))<<3)]);
    }
    #pragma unroll
    for (int n = 0; n < NR; ++n){
      int col = wn*(BN/4) + n*16 + lr;
      b[n] = *reinterpret_cast<const short8v*>(&Bs[col*128 + ((kc ^ (col&7))<<3)]);
    }
    #pragma unroll
    for (int m = 0; m < 4; ++m)
      #pragma unroll
      for (int n = 0; n < NR; ++n)
        acc[m][n] = __builtin_amdgcn_mfma_f32_16x16x32_bf16(b[n], a[m], acc[m][n], 0, 0, 0);
  }
  __syncthreads();   // Bs weight reads done -> reuse as repack buffer

  if constexpr (BN == 128){
    #pragma unroll
    for (int m = 0; m < 4; ++m){
      int row = wm*64 + m*16 + lr;
      #pragma unroll
      for (int n = 0; n < NR; ++n){
        int col0 = wn*32 + n*16 + lk*4;
        float4 b4 = *reinterpret_cast<const float4*>(&bias[col0]);
        float y0 = acc[m][n][0] + b4.x, y1 = acc[m][n][1] + b4.y;
        float y2 = acc[m][n][2] + b4.z, y3 = acc[m][n][3] + b4.w;
        if (RELU_OUT){
          y0 = fmaxf(y0,0.f); y1 = fmaxf(y1,0.f); y2 = fmaxf(y2,0.f); y3 = fmaxf(y3,0.f);
        }
        uint2 pk; pk.x = pk2(y0,y1); pk.y = pk2(y2,y3);
        int c16 = col0 >> 3;
        *reinterpret_cast<uint2*>(&Bs[row*128 + ((c16 ^ (row&7))<<3) + (col0&7)]) = pk;
      }
    }
    __syncthreads();
    float g = 1.f, og = 0.f;
    if (SKIP){ float sv = *Ar.skip_s[part]; g = 1.f/(1.f + expf(-sv)); og = 1.f - g; }
    unsigned short* out = (unsigned short*)Ar.Y[part];
    const unsigned short* skip_x = Ar.skip_x[part];
    for (int c = t; c < 128*16; c += 512){
      int r = c >> 4, c16 = c & 15;
      int gr = row0 + r;
      if (gr >= N) continue;
      short8v v = *reinterpret_cast<const short8v*>(&Bs[r*128 + ((c16 ^ (r&7))<<3)]);
      if (SKIP){
        short8v s8 = *reinterpret_cast<const short8v*>(&skip_x[(size_t)gr*128 + c16*8]);
        short8v o8;
        #pragma unroll
        for (int i = 0; i < 8; ++i)
          o8[i] = (short)f2bf(g*bf2f((unsigned short)v[i]) + og*bf2f((unsigned short)s8[i]));
        *reinterpret_cast<short8v*>(&out[(size_t)gr*128 + c16*8]) = o8;
      } else {
        *reinterpret_cast<short8v*>(&out[(size_t)gr*128 + c16*8]) = v;
      }
    }
  } else {
    // BN==64: fp32 repack (32 KB), fp32 coalesced out (classifier)
    float* Bf = (float*)Braw;
    #pragma unroll
    for (int m = 0; m < 4; ++m){
      int row = wm*64 + m*16 + lr;
      #pragma unroll
      for (int n = 0; n < NR; ++n){
        int col0 = wn*16 + n*16 + lk*4;
        float4 b4 = *reinterpret_cast<const float4*>(&bias[col0]);
        float4 y;
        y.x = acc[m][n][0] + b4.x; y.y = acc[m][n][1] + b4.y;
        y.z = acc[m][n][2] + b4.z; y.w = acc[m][n][3] + b4.w;
        int cf = col0 >> 2;
        *reinterpret_cast<float4*>(&Bf[row*64 + ((cf ^ (row&7))<<2)]) = y;
      }
    }
    __syncthreads();
    float* out = (float*)Ar.Y[part];
    for (int c = t; c < 128*16; c += 512){
      int r = c >> 4, cf = c & 15;
      int gr = row0 + r;
      if (gr >= N) continue;
      float4 v = *reinterpret_cast<const float4*>(&Bf[r*64 + ((cf ^ (r&7))<<2)]);
      *reinterpret_cast<float4*>(&out[(size_t)gr*64 + cf*4]) = v;
    }
  }
}

struct QkvArgs {
  const unsigned short* X[2];
  const unsigned short* WT[2][3];
  const float* bias[2][3];
  unsigned short* out[2][3];
  int N[2];
  int blocks0;
};

// Fused QKV (512 threads): stage X once; per weight: stage B, MFMA (swapped), repack, store.
__global__ __launch_bounds__(512) void qkv_kernel(QkvArgs Ar)
{
  __shared__ __align__(16) short As[128*128];
  __shared__ __align__(16) short Bs[128*128];
  const int t = threadIdx.x;
  const int part = (blockIdx.x < Ar.blocks0) ? 0 : 1;
  const int bid = part ? (blockIdx.x - Ar.blocks0) : blockIdx.x;
  const unsigned short* X = Ar.X[part];
  const int N = Ar.N[part];
  const int row0 = bid*128;
  for (int c = t; c < 128*16; c += 512){
    int r = c >> 4, c16 = c & 15;
    int gr = row0 + r;
    short8v v = (gr < N) ? *reinterpret_cast<const short8v*>(&X[(size_t)gr*128 + c16*8])
                         : (short8v)0;
    *reinterpret_cast<short8v*>(&As[r*128 + ((c16 ^ (r&7))<<3)]) = v;
  }
  const int lane = t & 63, wid = t >> 6;
  const int wm = wid >> 2, wn = wid & 3;
  const int lr = lane & 15, lk = lane >> 4;
  #pragma unroll
  for (int s = 0; s < 3; ++s){
    __syncthreads();                   // A staged (s=0) / prev readout done
    stage_w(Bs, Ar.WT[part][s], t, 128);
    __syncthreads();
    f32x4 acc[4][2] = {};
    #pragma unroll
    for (int kk = 0; kk < 4; ++kk){
      int kc = kk*4 + lk;
      short8v a[4], b[2];
      #pragma unroll
      for (int m = 0; m < 4; ++m){
        int r = wm*64 + m*16 + lr;
        a[m] = *reinterpret_cast<const short8v*>(&As[r*128 + ((kc ^ (r&7))<<3)]);
      }
      #pragma unroll
      for (int n = 0; n < 2; ++n){
        int col = wn*32 + n*16 + lr;
        b[n] = *reinterpret_cast<const short8v*>(&Bs[col*128 + ((kc ^ (col&7))<<3)]);
      }
      #pragma unroll
      for (int m = 0; m < 4; ++m)
        #pragma unroll
        for (int n = 0; n < 2; ++n)
          acc[m][n] = __builtin_amdgcn_mfma_f32_16x16x32_bf16(b[n], a[m], acc[m][n], 0, 0, 0);
    }
    __syncthreads();                   // weight reads done -> repack into Bs
    const float* bi = Ar.bias[part][s];
    #pragma unroll
    for (int m = 0; m < 4; ++m){
      int row = wm*64 + m*16 + lr;
      #pragma unroll
      for (int n = 0; n < 2; ++n){
        int col0 = wn*32 + n*16 + lk*4;
        float4 b4 = *reinterpret_cast<const float4*>(&bi[col0]);
        uint2 pk;
        pk.x = pk2(acc[m][n][0] + b4.x, acc[m][n][1] + b4.y);
        pk.y = pk2(acc[m][n][2] + b4.z, acc[m][n][3] + b4.w);
        int c16 = col0 >> 3;
        *reinterpret_cast<uint2*>(&Bs[row*128 + ((c16 ^ (row&7))<<3) + (col0&7)]) = pk;
      }
    }
    __syncthreads();
    unsigned short* out = Ar.out[part][s];
    for (int c = t; c < 128*16; c += 512){
      int r = c >> 4, c16 = c & 15;
      int gr = row0 + r;
      if (gr >= N) continue;
      short8v v = *reinterpret_cast<const short8v*>(&Bs[r*128 + ((c16 ^ (r&7))<<3)]);
      *reinterpret_cast<short8v*>(&out[(size_t)gr*128 + c16*8]) = v;
    }
  }
}

struct AttnArgs {
  unsigned short* QA[2];
  const unsigned short* K[2];
  const unsigned short* V[2];
  const int* rp[2];
  const int* slots[2];
  const float* relp[2];
  int N[2];
  int blocks0;
};

// Fused attention (both directions in one launch): thread per (dst node, head).
__global__ void attn_gather_kernel(AttnArgs Ar){
  const int part = (blockIdx.x < Ar.blocks0) ? 0 : 1;
  const int bid = part ? (blockIdx.x - Ar.blocks0) : blockIdx.x;
  int idx = bid*256 + threadIdx.x;
  const int N = Ar.N[part];
  if (idx >= N*8) return;
  int h = idx & 7, n = idx >> 3;
  unsigned short* QA = Ar.QA[part];
  const unsigned short* K = Ar.K[part];
  const unsigned short* V = Ar.V[part];
  float q[16];
  StBF16::ld16(&QA[(size_t)n*128 + h*16], q);
  float scale_h = Ar.relp[part][h]*0.25f;
  float m = -INFINITY, s = 0.f, acc[16];
  #pragma unroll
  for (int i = 0; i < 16; ++i) acc[i] = 0.f;
  int b = Ar.rp[part][n], e = Ar.rp[part][n+1];
  const int* slots = Ar.slots[part];
  for (int j = b; j < e; ++j){
    int sv = slots[j];
    float kf[16], vf[16];
    StBF16::ld16(&K[(size_t)sv*128 + h*16], kf);
    float a = 0.f;
    #pragma unroll
    for (int i = 0; i < 16; ++i) a += q[i]*kf[i];
    a *= scale_h;
    float mn = fmaxf(m, a);
    float c = expf(m - mn);
    float p = expf(a - mn);
    StBF16::ld16(&V[(size_t)sv*128 + h*16], vf);
    s = s*c + p;
    #pragma unroll
    for (int i = 0; i < 16; ++i) acc[i] = acc[i]*c + p*vf[i];
    m = mn;
  }
  float inv = 1.f/(s + 1e-16f);
  #pragma unroll
  for (int i = 0; i < 16; ++i) QA[(size_t)n*128 + h*16 + i] = f2bf(acc[i]*inv);
}

struct Ptrs {
  const float *x_author, *x_paper, *win_w, *win_b, *kqv_w, *kqv_b, *a_w, *a_b;
  const float *skip, *rel_a, *rel_m, *rel_p, *out_w, *out_b;
  const int *src0, *dst0, *src1, *dst1;
};

static void run_pipeline(const Ptrs& P, float* d_out, char* ws, hipStream_t stream){
  using BF = unsigned short;
  size_t off = 0;
  auto alloc = [&](size_t bytes) -> void* {
    void* p = ws + off;
    off += (bytes + 255) & ~(size_t)255;
    return p;
  };
  BF* X0 = (BF*)alloc((size_t)Na*128*2);
  BF* X1 = (BF*)alloc((size_t)Np*128*2);
  BF* Q0 = (BF*)alloc((size_t)Na*128*2);   // Q -> agg in place
  BF* Q1 = (BF*)alloc((size_t)Np*128*2);
  BF* K0 = (BF*)alloc((size_t)Na*128*2);
  BF* K1 = (BF*)alloc((size_t)Np*128*2);
  BF* V0 = (BF*)alloc((size_t)Na*128*2);
  BF* V1 = (BF*)alloc((size_t)Np*128*2);
  float* effw = (float*)alloc((size_t)8*16384*4);
  float* effb = (float*)alloc((size_t)8*128*4);
  BF* wbf = (BF*)alloc((size_t)19*16384*2);
  int* rp0   = (int*)alloc((size_t)(Np+1)*4);
  int* cur0  = (int*)alloc((size_t)Np*4);
  int* slot0 = (int*)alloc((size_t)E*4);
  int* rp1   = (int*)alloc((size_t)(Na+1)*4);
  int* cur1  = (int*)alloc((size_t)Na*4);
  int* slot1 = (int*)alloc((size_t)E*4);
  int* bsum  = (int*)alloc((size_t)1024*4);

  auto cdiv = [](int a, int b){ return (a+b-1)/b; };
  const int geE = cdiv(E, 256);
  const int ga = cdiv(Na, 128), gp = cdiv(Np, 128);
  const int sb0 = cdiv(Np, SCAN_TILE), sb1 = cdiv(Na, SCAN_TILE);

  eff_w_kernel<<<512, 256, 0, stream>>>(P.kqv_w, P.kqv_b, P.rel_a, P.rel_m, effw, effb);

  // weight prep: slots 0-1 win, 2-5 Q(l,t), 6-9 K, 10-13 V, 14-17 a_w, 18 out_w
  PrepSrc ps;
  ps.s[0] = P.win_w; ps.s[1] = P.win_w + 16384;
  for (int l = 0; l < 2; ++l)
    for (int t = 0; t < 2; ++t){
      ps.s[2 + l*2 + t]  = P.kqv_w + (size_t)((l*2+t)*3+1)*16384;
      ps.s[6 + l*2 + t]  = effw + (size_t)(l*4+t*2+0)*16384;
      ps.s[10 + l*2 + t] = effw + (size_t)(l*4+t*2+1)*16384;
      ps.s[14 + l*2 + t] = P.a_w + (size_t)(l*2+t)*16384;
    }
  ps.s[18] = P.out_w;
  prep_w_kernel<<<cdiv(19*16384,256),256,0,stream>>>(ps, wbf);

  // ---- CSR build ----
  zero_int_kernel<<<512,256,0,stream>>>(cur0, Np);
  zero_int_kernel<<<512,256,0,stream>>>(cur1, Na);
  hist_kernel<<<geE,256,0,stream>>>(P.dst0, cur0, E);
  hist_kernel<<<geE,256,0,stream>>>(P.dst1, cur1, E);
  scan_a<<<sb0,256,0,stream>>>(cur0, bsum, Np);
  scan_b<<<1,1024,0,stream>>>(bsum, sb0);
  scan_c<<<sb0,256,0,stream>>>(cur0, bsum, rp0, Np);
  scan_a<<<sb1,256,0,stream>>>(cur1, bsum, Na);
  scan_b<<<1,1024,0,stream>>>(bsum, sb1);
  scan_c<<<sb1,256,0,stream>>>(cur1, bsum, rp1, Na);
  fill_slots_kernel<<<geE,256,0,stream>>>(P.src0, P.dst0, cur0, slot0, E);
  fill_slots_kernel<<<geE,256,0,stream>>>(P.src1, P.dst1, cur1, slot1, E);

  auto W = [&](int s){ return wbf + (size_t)s*16384; };

  // input projections + relu (fp32 in, bf16 out) — merged pair
  {
    GemmArgs g{};
    g.X[0] = P.x_author; g.X[1] = P.x_paper;
    g.WT[0] = W(0); g.WT[1] = W(1);
    g.bias[0] = P.win_b; g.bias[1] = P.win_b + 128;
    g.Y[0] = X0; g.Y[1] = X1;
    g.N[0] = Na; g.N[1] = Np; g.blocks0 = ga;
    gemm_kernel<128,0,1,0,StF32><<<ga+gp,512,0,stream>>>(g);
  }

  const int ab0 = cdiv(Np*8,256), ab1 = cdiv(Na*8,256);

  for (int l = 0; l < L; ++l){
    QkvArgs q{};
    q.X[0] = X0; q.X[1] = X1;
    for (int t2 = 0; t2 < 2; ++t2){
      q.WT[t2][0] = W(2+l*2+t2); q.WT[t2][1] = W(6+l*2+t2); q.WT[t2][2] = W(10+l*2+t2);
      q.bias[t2][0] = P.kqv_b + ((l*2+t2)*3+1)*128;
      q.bias[t2][1] = effb + (l*4+t2*2+0)*128;
      q.bias[t2][2] = effb + (l*4+t2*2+1)*128;
    }
    q.out[0][0] = Q0; q.out[0][1] = K0; q.out[0][2] = V0;
    q.out[1][0] = Q1; q.out[1][1] = K1; q.out[1][2] = V1;
    q.N[0] = Na; q.N[1] = Np; q.blocks0 = ga;
    qkv_kernel<<<ga+gp,512,0,stream>>>(q);

    AttnArgs a{};
    a.QA[0] = Q1; a.K[0] = K0; a.V[0] = V0; a.rp[0] = rp0; a.slots[0] = slot0;
    a.relp[0] = P.rel_p + (l*2+0)*8; a.N[0] = Np;
    a.QA[1] = Q0; a.K[1] = K1; a.V[1] = V1; a.rp[1] = rp1; a.slots[1] = slot1;
    a.relp[1] = P.rel_p + (l*2+1)*8; a.N[1] = Na;
    a.blocks0 = ab0;
    attn_gather_kernel<<<ab0+ab1,256,0,stream>>>(a);

    GemmArgs g{};
    g.X[0] = Q0; g.X[1] = Q1;
    g.WT[0] = W(14+l*2+0); g.WT[1] = W(14+l*2+1);
    g.bias[0] = P.a_b + (l*2+0)*128; g.bias[1] = P.a_b + (l*2+1)*128;
    g.Y[0] = X0; g.Y[1] = X1;
    g.skip_x[0] = X0; g.skip_x[1] = X1;
    g.skip_s[0] = P.skip + (l*2+0); g.skip_s[1] = P.skip + (l*2+1);
    g.N[0] = Na; g.N[1] = Np; g.blocks0 = ga;
    gemm_kernel<128,1,0,1,StBF16><<<ga+gp,512,0,stream>>>(g);
  }

  {
    GemmArgs g{};
    g.X[0] = X0; g.X[1] = nullptr;
    g.WT[0] = W(18); g.WT[1] = nullptr;
    g.bias[0] = P.out_b; g.bias[1] = nullptr;
    g.Y[0] = d_out; g.Y[1] = nullptr;
    g.N[0] = Na; g.N[1] = 0; g.blocks0 = ga;
    gemm_kernel<64,0,0,0,StBF16><<<ga,512,0,stream>>>(g);
  }
}

static size_t plan_bytes(){
  auto al = [](size_t x){ return (x + 255) & ~(size_t)255; };
  size_t t = 0;
  t += 4*(al((size_t)Na*128*2) + al((size_t)Np*128*2));   // X,Q,K,V bf16
  t += al((size_t)8*16384*4) + al((size_t)8*128*4) + al((size_t)19*16384*2);
  t += al((size_t)(Np+1)*4) + al((size_t)Np*4) + al((size_t)E*4);
  t += al((size_t)(Na+1)*4) + al((size_t)Na*4) + al((size_t)E*4);
  t += al((size_t)1024*4);
  return t;
}

} // namespace

extern "C" void kernel_launch(void* const* d_in, const int* in_sizes, int n_in,
                              void* d_out, int out_size, void* d_ws, size_t ws_size,
                              hipStream_t stream){
  Ptrs P;
  P.x_author = (const float*)d_in[0];
  P.x_paper  = (const float*)d_in[1];
  P.win_w = (const float*)d_in[2];
  P.win_b = (const float*)d_in[3];
  P.kqv_w = (const float*)d_in[4];
  P.kqv_b = (const float*)d_in[5];
  P.a_w   = (const float*)d_in[6];
  P.a_b   = (const float*)d_in[7];
  P.skip  = (const float*)d_in[8];
  P.rel_a = (const float*)d_in[9];
  P.rel_m = (const float*)d_in[10];
  P.rel_p = (const float*)d_in[11];
  P.out_w = (const float*)d_in[12];
  P.out_b = (const float*)d_in[13];
  P.src0 = (const int*)d_in[14];
  P.dst0 = (const int*)d_in[15];
  P.src1 = (const int*)d_in[16];
  P.dst1 = (const int*)d_in[17];

  if (ws_size >= plan_bytes()){
    run_pipeline(P, (float*)d_out, (char*)d_ws, stream);
  } else {
    diag_kernel<<<1,1,0,stream>>>((float*)d_out, (float)((double)ws_size/1.0e6));
  }
}